// Round 1
// baseline (1831.668 us; speedup 1.0000x reference)
//
#include <hip/hip_runtime.h>
#include <hip/hip_bf16.h>
#include <stdint.h>

// InvBlock: out = concat(u_new, v_new)
//   v_mid = tanh(u_old @ W1^T + b1); v_new = v_old + 0.1 * (v_mid @ W1)
//   u_mid = tanh(v_new @ W0^T + b0); u_new = u_old - 0.1 * (u_mid @ W0)
// Strategy: bf16 MFMA GEMMs (m97 structure: 128x128 tile, BK=64, 4 waves,
// 16x16x32 mfma, global_load_lds width-16 staging), fused epilogues.

typedef __attribute__((ext_vector_type(8))) short short8;   // 8 bf16 = 4 VGPRs
typedef __attribute__((ext_vector_type(4))) float f32x4;    // mfma accumulator

#define DEVINL __device__ __forceinline__

DEVINL ushort f2b(float f) {  // fp32 -> bf16 bits, round-to-nearest-even
  union { float f; uint32_t u; } v; v.f = f;
  uint32_t u = v.u;
  return (ushort)((u + 0x7fffu + ((u >> 16) & 1u)) >> 16);
}

DEVINL float fast_tanh(float x) {
  x = fminf(10.0f, fmaxf(-10.0f, x));
  float e = __expf(2.0f * x);
  return (e - 1.0f) * __builtin_amdgcn_rcpf(e + 1.0f);
}

DEVINL void gload16(const ushort* g, ushort* l) {
  // async global->LDS, 16B per lane; LDS dest is wave-uniform base + lane*16
  __builtin_amdgcn_global_load_lds(
      (const __attribute__((address_space(1))) void*)g,
      (__attribute__((address_space(3))) void*)l, 16, 0, 0);
}

constexpr int BM = 128, BN = 128, BK = 64;

// A: M x K bf16 row-major.  Bt: N x K bf16 row-major (i.e. B transposed).
// MODE 0: Tout[m,n] = bf16(tanh(acc + bias[n]))            (ld = N)
// MODE 1: o = xres[m*4096+n] + step*acc -> outres fp32, vbout bf16 (ld = N)
// MODE 2: same as 1 but no vbout
template<int MODE>
__global__ __launch_bounds__(256)
void gemm_bt(const ushort* __restrict__ A, const ushort* __restrict__ Bt,
             const float* __restrict__ bias, ushort* __restrict__ Tout,
             const float* __restrict__ xres, float* __restrict__ outres,
             ushort* __restrict__ vbout, float step, int M, int N, int K)
{
  __shared__ __align__(16) ushort lA[BM * BK];
  __shared__ __align__(16) ushort lB[BN * BK];

  const int tid  = threadIdx.x;
  const int wave = tid >> 6;
  const int lane = tid & 63;
  const int wr = wave >> 1, wc = wave & 1;   // 2x2 waves, 64x64 out each

  const int m0 = blockIdx.y * BM;
  const int n0 = blockIdx.x * BN;

  // staging: tile = 128 rows x 64 bf16 = 1024 chunks of 16B; 4 issues/thread
  const ushort* ag = A  + (size_t)(m0 + (tid >> 3)) * K + (tid & 7) * 8;
  const ushort* bg = Bt + (size_t)(n0 + (tid >> 3)) * K + (tid & 7) * 8;
  ushort* lAw = lA + wave * 512;   // wave-uniform LDS base (elements)
  ushort* lBw = lB + wave * 512;

  const int lr = lane & 15;          // fragment row (A) / col (B)
  const int kq = (lane >> 4) * 8;    // k sub-offset within 32

  f32x4 acc[4][4] = {};

  const int kt_count = K / BK;
  for (int kt = 0; kt < kt_count; ++kt) {
    __syncthreads();                 // previous compute done before overwrite
#pragma unroll
    for (int j = 0; j < 4; ++j) {
      gload16(ag + (size_t)j * 32 * K, lAw + j * 2048);
      gload16(bg + (size_t)j * 32 * K, lBw + j * 2048);
    }
    ag += BK; bg += BK;
    __syncthreads();                 // implies vmcnt(0): tiles resident
#pragma unroll
    for (int ks = 0; ks < 2; ++ks) {
      short8 af[4], bf[4];
#pragma unroll
      for (int i = 0; i < 4; ++i)
        af[i] = *(const short8*)&lA[(wr * 64 + i * 16 + lr) * BK + ks * 32 + kq];
#pragma unroll
      for (int i = 0; i < 4; ++i)
        bf[i] = *(const short8*)&lB[(wc * 64 + i * 16 + lr) * BK + ks * 32 + kq];
#pragma unroll
      for (int mi = 0; mi < 4; ++mi)
#pragma unroll
        for (int ni = 0; ni < 4; ++ni)
          acc[mi][ni] = __builtin_amdgcn_mfma_f32_16x16x32_bf16(
              af[mi], bf[ni], acc[mi][ni], 0, 0, 0);
    }
  }

  // epilogue: D col = lane&15, row = (lane>>4)*4 + r   [verified m89/m91]
  const int mw = m0 + wr * 64;
  const int nw = n0 + wc * 64;
#pragma unroll
  for (int mi = 0; mi < 4; ++mi) {
#pragma unroll
    for (int ni = 0; ni < 4; ++ni) {
      const int col = nw + ni * 16 + lr;
      if (MODE == 0) {
        const float bv = bias[col];
#pragma unroll
        for (int r = 0; r < 4; ++r) {
          const int row = mw + mi * 16 + (lane >> 4) * 4 + r;
          Tout[(size_t)row * N + col] = f2b(fast_tanh(acc[mi][ni][r] + bv));
        }
      } else {
#pragma unroll
        for (int r = 0; r < 4; ++r) {
          const int row = mw + mi * 16 + (lane >> 4) * 4 + r;
          const size_t oi = (size_t)row * 4096 + col;
          const float v = fmaf(step, acc[mi][ni][r], xres[oi]);
          outres[oi] = v;
          if (MODE == 1) vbout[(size_t)row * N + col] = f2b(v);
        }
      }
    }
  }
}

// u_b[m, 0:2048] = bf16(x[m, 0:2048])   (x has ld 4096)
__global__ void cast_strided_half(const float* __restrict__ x,
                                  ushort* __restrict__ dst)
{
  const int i = blockIdx.x * blockDim.x + threadIdx.x;   // [0, 16384*512)
  const int row = i >> 9;
  const int c4  = (i & 511) * 4;
  const float4 v = *(const float4*)&x[(size_t)row * 4096 + c4];
  ushort4 o;
  o.x = f2b(v.x); o.y = f2b(v.y); o.z = f2b(v.z); o.w = f2b(v.w);
  *(ushort4*)&dst[(size_t)row * 2048 + c4] = o;
}

// W (4096 x 2048 fp32) -> Wb (4096 x 2048 bf16) and Wt (2048 x 4096 bf16)
__global__ void pack_w(const float* __restrict__ W,
                       ushort* __restrict__ Wb, ushort* __restrict__ Wt)
{
  __shared__ float tile[32][33];
  const int bx = blockIdx.x * 32;   // col in W
  const int by = blockIdx.y * 32;   // row in W
  const int tx = threadIdx.x, ty = threadIdx.y;   // block 32x8
#pragma unroll
  for (int j = ty; j < 32; j += 8) {
    const float v = W[(size_t)(by + j) * 2048 + bx + tx];
    tile[j][tx] = v;
    Wb[(size_t)(by + j) * 2048 + bx + tx] = f2b(v);
  }
  __syncthreads();
#pragma unroll
  for (int j = ty; j < 32; j += 8) {
    Wt[(size_t)(bx + j) * 4096 + by + tx] = f2b(tile[tx][j]);
  }
}

extern "C" void kernel_launch(void* const* d_in, const int* in_sizes, int n_in,
                              void* d_out, int out_size, void* d_ws, size_t ws_size,
                              hipStream_t stream)
{
  const float* x  = (const float*)d_in[0];   // 16384 x 4096
  const float* W0 = (const float*)d_in[1];   // 4096 x 2048
  const float* b0 = (const float*)d_in[2];   // 4096
  const float* W1 = (const float*)d_in[3];   // 4096 x 2048
  const float* b1 = (const float*)d_in[4];   // 4096
  float* out = (float*)d_out;                // 16384 x 4096

  const int Mrows = 16384, H2 = 4096, Hh = 2048;

  // workspace layout (256 MiB total)
  uint8_t* ws = (uint8_t*)d_ws;
  ushort* T   = (ushort*)ws;                                   // 128 MiB
  ushort* Ab  = (ushort*)(ws + (size_t)134217728);             //  64 MiB (u_b, then v_b)
  ushort* W0b = (ushort*)(ws + (size_t)134217728 + 67108864);  //  16 MiB
  ushort* W0t = W0b + 8388608;
  ushort* W1b = W0t + 8388608;
  ushort* W1t = W1b + 8388608;

  cast_strided_half<<<32768, 256, 0, stream>>>(x, Ab);
  dim3 pw_grid(64, 128), pw_blk(32, 8);
  pack_w<<<pw_grid, pw_blk, 0, stream>>>(W1, W1b, W1t);
  pack_w<<<pw_grid, pw_blk, 0, stream>>>(W0, W0b, W0t);

  dim3 blk(256);
  dim3 g1(H2 / BN, Mrows / BM);   // 32 x 128
  dim3 g2(Hh / BN, Mrows / BM);   // 16 x 128

  // T1 = tanh(u_old @ W1^T + b1)
  gemm_bt<0><<<g1, blk, 0, stream>>>(Ab, W1b, b1, T,
                                     nullptr, nullptr, nullptr, 0.f,
                                     Mrows, H2, Hh);
  // v_new = v_old + 0.1*(T1 @ W1)  -> out[:,2048:] fp32 + Ab bf16
  gemm_bt<1><<<g2, blk, 0, stream>>>(T, W1t, nullptr, nullptr,
                                     x + Hh, out + Hh, Ab, 0.1f,
                                     Mrows, Hh, H2);
  // T2 = tanh(v_new @ W0^T + b0)
  gemm_bt<0><<<g1, blk, 0, stream>>>(Ab, W0b, b0, T,
                                     nullptr, nullptr, nullptr, 0.f,
                                     Mrows, H2, Hh);
  // u_new = u_old - 0.1*(T2 @ W0)  -> out[:,:2048] fp32
  gemm_bt<2><<<g2, blk, 0, stream>>>(T, W0t, nullptr, nullptr,
                                     x, out, nullptr, -0.1f,
                                     Mrows, Hh, H2);
}

// Round 2
// 1405.181 us; speedup vs baseline: 1.3035x; 1.3035x over previous
//
#include <hip/hip_runtime.h>
#include <hip/hip_bf16.h>
#include <stdint.h>

// InvBlock: out = concat(u_new, v_new)
//   v_mid = tanh(u_old @ W1^T + b1); v_new = v_old + 0.1 * (v_mid @ W1)
//   u_mid = tanh(v_new @ W0^T + b0); u_new = u_old - 0.1 * (u_mid @ W0)
// GEMM: 256x256 tile, BK=64, 8 waves, 8-phase counted-vmcnt schedule (T3+T4)
// + LDS XOR swizzle (T2) + setprio (T5) + XCD swizzle (T1). m201 template.

typedef __attribute__((ext_vector_type(8))) short short8;   // 8 bf16 = 4 VGPRs
typedef __attribute__((ext_vector_type(4))) float f32x4;

#define DEVINL __device__ __forceinline__

DEVINL ushort f2b(float f) {  // fp32 -> bf16 bits, RNE
  union { float f; uint32_t u; } v; v.f = f;
  uint32_t u = v.u;
  return (ushort)((u + 0x7fffu + ((u >> 16) & 1u)) >> 16);
}

DEVINL float fast_tanh(float x) {
  x = fminf(10.0f, fmaxf(-10.0f, x));
  float e = __expf(2.0f * x);
  return (e - 1.0f) * __builtin_amdgcn_rcpf(e + 1.0f);
}

DEVINL void gload16(const ushort* g, ushort* l) {
  __builtin_amdgcn_global_load_lds(
      (const __attribute__((address_space(1))) void*)g,
      (__attribute__((address_space(3))) void*)l, 16, 0, 0);
}

DEVINL void read_af(short8 (&a)[4][2], const char* p, int kb0, int kb1) {
#pragma unroll
  for (int mi = 0; mi < 4; ++mi) {
    a[mi][0] = *(const short8*)(p + mi * 2048 + kb0);
    a[mi][1] = *(const short8*)(p + mi * 2048 + kb1);
  }
}
DEVINL void read_bf(short8 (&b)[2][2], const char* p, int kb0, int kb1) {
#pragma unroll
  for (int ni = 0; ni < 2; ++ni) {
    b[ni][0] = *(const short8*)(p + ni * 2048 + kb0);
    b[ni][1] = *(const short8*)(p + ni * 2048 + kb1);
  }
}

template<int MH, int NH>
DEVINL void mfma_quad(f32x4 (&acc)[8][4], const short8 (&a)[4][2],
                      const short8 (&b)[2][2]) {
#pragma unroll
  for (int ks = 0; ks < 2; ++ks)
#pragma unroll
    for (int mi = 0; mi < 4; ++mi)
#pragma unroll
      for (int ni = 0; ni < 2; ++ni)
        acc[MH * 4 + mi][NH * 2 + ni] = __builtin_amdgcn_mfma_f32_16x16x32_bf16(
            a[mi][ks], b[ni][ks], acc[MH * 4 + mi][NH * 2 + ni], 0, 0, 0);
}

// A: M x K bf16 row-major.  Bt: N x K bf16 row-major.
// MODE 0: Tout[m,n] = bf16(tanh(acc + bias[n]))            (ld = N)
// MODE 1: o = xres[m*4096+n] + step*acc -> outres fp32 + vbout bf16 (ld = N)
// MODE 2: same as 1 but no vbout
template<int MODE>
__global__ __launch_bounds__(512, 2)
void gemm256(const ushort* __restrict__ A, const ushort* __restrict__ Bt,
             const float* __restrict__ bias, ushort* __restrict__ Tout,
             const float* __restrict__ xres, float* __restrict__ outres,
             ushort* __restrict__ vbout, float step, int M, int N, int K)
{
  __shared__ ushort ldsU[65536];   // 128 KiB: [buf:2][A 32KB | B 32KB]
  const char* ldsc = (const char*)ldsU;

  const int tid  = threadIdx.x;
  const int wave = tid >> 6, lane = tid & 63;
  const int wr = wave >> 2, wc = wave & 3;       // 2 x 4 wave grid
  const int lr = lane & 15, hi = lane >> 4;

  // T1: XCD-aware block swizzle (nwg % 8 == 0 for all our shapes)
  const int GX = gridDim.x;
  const int nwg = GX * gridDim.y;
  const int lin = blockIdx.y * GX + blockIdx.x;
  const int swz = (lin & 7) * (nwg >> 3) + (lin >> 3);
  const int by = swz / GX, bx = swz - by * GX;
  const int m0 = by * 256, n0 = bx * 256;

  // ---- staging source offsets (inverse-swizzled global source, rule #21)
  // LDS halves: A-half h = rows {wr*128 + h*64 + 0..63}; B-half h = cols
  // {wc*64 + h*32 + 0..31}; linear layout [r'|c'][k], 128B rows, swizzle
  // byte ^= ((row&7)<<4).
  const int kb_st = ((tid & 7) * 16) ^ (((tid >> 3) & 7) << 4);
  int offA[2][2], offB[2][2];   // [half][j], constant-indexed only
#pragma unroll
  for (int j = 0; j < 2; ++j) {
    const int rp = j * 64 + (tid >> 3);
#pragma unroll
    for (int h = 0; h < 2; ++h) {
      offA[h][j] = (m0 + (rp >> 6) * 128 + h * 64 + (rp & 63)) * K + (kb_st >> 1);
      offB[h][j] = (n0 + (rp >> 5) * 64 + h * 32 + (rp & 31)) * K + (kb_st >> 1);
    }
  }

#define STAGE_A(buf, half, t) do {                                             \
    gload16(A + (size_t)offA[half][0] + (size_t)(t) * 64,                      \
            ldsU + (buf) * 32768 + (half) * 8192 + tid * 8);                   \
    gload16(A + (size_t)offA[half][1] + (size_t)(t) * 64,                      \
            ldsU + (buf) * 32768 + (half) * 8192 + 4096 + tid * 8);            \
  } while (0)
#define STAGE_B(buf, half, t) do {                                             \
    gload16(Bt + (size_t)offB[half][0] + (size_t)(t) * 64,                     \
            ldsU + (buf) * 32768 + 16384 + (half) * 8192 + tid * 8);           \
    gload16(Bt + (size_t)offB[half][1] + (size_t)(t) * 64,                     \
            ldsU + (buf) * 32768 + 16384 + (half) * 8192 + 4096 + tid * 8);    \
  } while (0)

  // ---- fragment-read lane bases (row&7 == lane&7 for every fragment)
  const int xm = (lane & 7) << 4;
  const int kbr0 = (hi * 16) ^ xm;
  const int kbr1 = (64 + hi * 16) ^ xm;
  const int raA = (wr * 64 + lr) * 128;
  const int raB = (wc * 32 + lr) * 128;
#define A_REG(buf, half) (ldsc + (buf) * 65536 + (half) * 16384 + raA)
#define B_REG(buf, half) (ldsc + (buf) * 65536 + 32768 + (half) * 16384 + raB)

  f32x4 acc[8][4] = {};
  short8 a0[4][2], a1[4][2], b0[2][2], b1[2][2];

#define PHASE_TAIL(MH, NH, AF, BF)                                             \
  __builtin_amdgcn_s_barrier();                                                \
  asm volatile("s_waitcnt lgkmcnt(0)" ::: "memory");                           \
  __builtin_amdgcn_sched_barrier(0);                                           \
  __builtin_amdgcn_s_setprio(1);                                               \
  mfma_quad<MH, NH>(acc, AF, BF);                                              \
  __builtin_amdgcn_s_setprio(0);                                               \
  __builtin_amdgcn_s_barrier();

  const int NT = K >> 6;        // 64-wide K tiles (even; NT/2 >= 2)
  const int NI = NT >> 1;

  // ---- prologue: buf0 <- tile0 (4 halves), buf1 <- tile1 {A0,B0,A1}
  STAGE_A(0, 0, 0); STAGE_A(0, 1, 0); STAGE_B(0, 0, 0); STAGE_B(0, 1, 0);
  STAGE_A(1, 0, 1); STAGE_B(1, 0, 1); STAGE_A(1, 1, 1);
  asm volatile("s_waitcnt vmcnt(6)" ::: "memory");   // buf0 resident
  __builtin_amdgcn_s_barrier();

  // ---- main loop: iteration i computes tiles 2i (buf0) and 2i+1 (buf1)
#pragma unroll 1
  for (int i = 0; i < NI - 1; ++i) {
    const int t = 2 * i;
    // P1: Q00 buf0
    read_af(a0, A_REG(0, 0), kbr0, kbr1);
    read_bf(b0, B_REG(0, 0), kbr0, kbr1);
    STAGE_B(1, 1, t + 1);
    PHASE_TAIL(0, 0, a0, b0)
    // P2: Q10 buf0
    read_af(a1, A_REG(0, 1), kbr0, kbr1);
    STAGE_A(0, 0, t + 2);
    PHASE_TAIL(1, 0, a1, b0)
    // P3: Q01 buf0
    read_bf(b1, B_REG(0, 1), kbr0, kbr1);
    STAGE_A(0, 1, t + 2);
    PHASE_TAIL(0, 1, a0, b1)
    // P4: Q11 buf0
    STAGE_B(0, 0, t + 2);
    asm volatile("s_waitcnt vmcnt(6)" ::: "memory");  // buf1(t+1) resident
    PHASE_TAIL(1, 1, a1, b1)
    // P5: Q00 buf1
    read_af(a0, A_REG(1, 0), kbr0, kbr1);
    read_bf(b0, B_REG(1, 0), kbr0, kbr1);
    STAGE_B(0, 1, t + 2);
    PHASE_TAIL(0, 0, a0, b0)
    // P6: Q10 buf1
    read_af(a1, A_REG(1, 1), kbr0, kbr1);
    STAGE_A(1, 0, t + 3);
    PHASE_TAIL(1, 0, a1, b0)
    // P7: Q01 buf1
    read_bf(b1, B_REG(1, 1), kbr0, kbr1);
    STAGE_A(1, 1, t + 3);
    PHASE_TAIL(0, 1, a0, b1)
    // P8: Q11 buf1
    STAGE_B(1, 0, t + 3);
    asm volatile("s_waitcnt vmcnt(6)" ::: "memory");  // buf0(t+2) resident
    PHASE_TAIL(1, 1, a1, b1)
  }

  // ---- peeled final iteration (tiles NT-2, NT-1): only P1 stages
  {
    const int t = NT - 2;
    read_af(a0, A_REG(0, 0), kbr0, kbr1);
    read_bf(b0, B_REG(0, 0), kbr0, kbr1);
    STAGE_B(1, 1, t + 1);
    PHASE_TAIL(0, 0, a0, b0)
    read_af(a1, A_REG(0, 1), kbr0, kbr1);
    PHASE_TAIL(1, 0, a1, b0)
    read_bf(b1, B_REG(0, 1), kbr0, kbr1);
    PHASE_TAIL(0, 1, a0, b1)
    asm volatile("s_waitcnt vmcnt(0)" ::: "memory");  // buf1.B1 landed
    PHASE_TAIL(1, 1, a1, b1)
    read_af(a0, A_REG(1, 0), kbr0, kbr1);
    read_bf(b0, B_REG(1, 0), kbr0, kbr1);
    PHASE_TAIL(0, 0, a0, b0)
    read_af(a1, A_REG(1, 1), kbr0, kbr1);
    PHASE_TAIL(1, 0, a1, b0)
    read_bf(b1, B_REG(1, 1), kbr0, kbr1);
    PHASE_TAIL(0, 1, a0, b1)
    PHASE_TAIL(1, 1, a1, b1)
  }

  // ---- epilogue: C row = m0+wr*128+MI*16+hi*4+r, col = n0+wc*64+NI*16+lr
  const int mrow0 = m0 + wr * 128 + hi * 4;
  const int ncol0 = n0 + wc * 64 + lr;
#pragma unroll
  for (int mi = 0; mi < 8; ++mi) {
#pragma unroll
    for (int ni = 0; ni < 4; ++ni) {
      const int col = ncol0 + ni * 16;
      if (MODE == 0) {
        const float bv = bias[col];
#pragma unroll
        for (int r = 0; r < 4; ++r) {
          const int row = mrow0 + mi * 16 + r;
          Tout[(size_t)row * N + col] = f2b(fast_tanh(acc[mi][ni][r] + bv));
        }
      } else {
#pragma unroll
        for (int r = 0; r < 4; ++r) {
          const int row = mrow0 + mi * 16 + r;
          const size_t oi = (size_t)row * 4096 + col;
          const float v = fmaf(step, acc[mi][ni][r], xres[oi]);
          outres[oi] = v;
          if (MODE == 1) vbout[(size_t)row * N + col] = f2b(v);
        }
      }
    }
  }
#undef STAGE_A
#undef STAGE_B
#undef A_REG
#undef B_REG
#undef PHASE_TAIL
}

// u_b[m, 0:2048] = bf16(x[m, 0:2048])   (x has ld 4096)
__global__ void cast_strided_half(const float* __restrict__ x,
                                  ushort* __restrict__ dst)
{
  const int i = blockIdx.x * blockDim.x + threadIdx.x;
  const int row = i >> 9;
  const int c4  = (i & 511) * 4;
  const float4 v = *(const float4*)&x[(size_t)row * 4096 + c4];
  ushort4 o;
  o.x = f2b(v.x); o.y = f2b(v.y); o.z = f2b(v.z); o.w = f2b(v.w);
  *(ushort4*)&dst[(size_t)row * 2048 + c4] = o;
}

// W (4096 x 2048 fp32) -> Wb (4096 x 2048 bf16) and Wt (2048 x 4096 bf16)
__global__ void pack_w(const float* __restrict__ W,
                       ushort* __restrict__ Wb, ushort* __restrict__ Wt)
{
  __shared__ float tile[32][33];
  const int bx = blockIdx.x * 32;
  const int by = blockIdx.y * 32;
  const int tx = threadIdx.x, ty = threadIdx.y;   // 32x8
#pragma unroll
  for (int j = ty; j < 32; j += 8) {
    const float v = W[(size_t)(by + j) * 2048 + bx + tx];
    tile[j][tx] = v;
    Wb[(size_t)(by + j) * 2048 + bx + tx] = f2b(v);
  }
  __syncthreads();
#pragma unroll
  for (int j = ty; j < 32; j += 8) {
    Wt[(size_t)(bx + j) * 4096 + by + tx] = f2b(tile[tx][j]);
  }
}

extern "C" void kernel_launch(void* const* d_in, const int* in_sizes, int n_in,
                              void* d_out, int out_size, void* d_ws, size_t ws_size,
                              hipStream_t stream)
{
  const float* x  = (const float*)d_in[0];   // 16384 x 4096
  const float* W0 = (const float*)d_in[1];   // 4096 x 2048
  const float* b0 = (const float*)d_in[2];
  const float* W1 = (const float*)d_in[3];
  const float* b1 = (const float*)d_in[4];
  float* out = (float*)d_out;                // 16384 x 4096

  const int Mrows = 16384, H2 = 4096, Hh = 2048;

  uint8_t* ws = (uint8_t*)d_ws;
  ushort* T   = (ushort*)ws;                                   // 128 MiB
  ushort* Ab  = (ushort*)(ws + (size_t)134217728);             //  64 MiB
  ushort* W0b = (ushort*)(ws + (size_t)134217728 + 67108864);
  ushort* W0t = W0b + 8388608;
  ushort* W1b = W0t + 8388608;
  ushort* W1t = W1b + 8388608;

  cast_strided_half<<<32768, 256, 0, stream>>>(x, Ab);
  dim3 pw_grid(64, 128), pw_blk(32, 8);
  pack_w<<<pw_grid, pw_blk, 0, stream>>>(W1, W1b, W1t);
  pack_w<<<pw_grid, pw_blk, 0, stream>>>(W0, W0b, W0t);

  dim3 blk(512);
  dim3 g1(H2 / 256, Mrows / 256);   // 16 x 64
  dim3 g2(Hh / 256, Mrows / 256);   //  8 x 64

  // T1 = tanh(u_old @ W1^T + b1)
  gemm256<0><<<g1, blk, 0, stream>>>(Ab, W1b, b1, T,
                                     nullptr, nullptr, nullptr, 0.f,
                                     Mrows, H2, Hh);
  // v_new = v_old + 0.1*(T1 @ W1)  -> out[:,2048:] fp32 + Ab bf16
  gemm256<1><<<g2, blk, 0, stream>>>(T, W1t, nullptr, nullptr,
                                     x + Hh, out + Hh, Ab, 0.1f,
                                     Mrows, Hh, H2);
  // T2 = tanh(v_new @ W0^T + b0)
  gemm256<0><<<g1, blk, 0, stream>>>(Ab, W0b, b0, T,
                                     nullptr, nullptr, nullptr, 0.f,
                                     Mrows, H2, Hh);
  // u_new = u_old - 0.1*(T2 @ W0)  -> out[:,:2048] fp32
  gemm256<2><<<g2, blk, 0, stream>>>(T, W0t, nullptr, nullptr,
                                     x, out, nullptr, -0.1f,
                                     Mrows, Hh, H2);
}